// Round 1
// baseline (355.748 us; speedup 1.0000x reference)
//
#include <hip/hip_runtime.h>
#include <hip/hip_bf16.h>
#include <cstdint>
#include <cstddef>

// Problem constants: B=4, N=4096, D=1024, H=16, HD=64
#define NB      4
#define NSEQ    4096
#define DM      1024
#define NTOK    16384          // B*N
#define QKV_N   3072           // 3*D

typedef __attribute__((ext_vector_type(8))) short short8_t;   // 8 x bf16 bits
typedef __attribute__((ext_vector_type(4))) float f32x4;

static __device__ __forceinline__ unsigned short f2bf(float f) {
    unsigned u = __builtin_bit_cast(unsigned, f);
    u += 0x7fffu + ((u >> 16) & 1u);          // RNE
    return (unsigned short)(u >> 16);
}

static __device__ __forceinline__ void async16(const void* g, void* l) {
    __builtin_amdgcn_global_load_lds(
        (const __attribute__((address_space(1))) void*)g,
        (__attribute__((address_space(3))) void*)l, 16, 0, 0);
}

// ---------------- fp32 -> bf16 convert (vectorized) ----------------
__global__ void cvt_f32_bf16(const float* __restrict__ in,
                             unsigned short* __restrict__ out, int n4) {
    int i = blockIdx.x * blockDim.x + threadIdx.x;
    if (i >= n4) return;
    float4 f = ((const float4*)in)[i];
    unsigned lo = (unsigned)f2bf(f.x) | ((unsigned)f2bf(f.y) << 16);
    unsigned hi = (unsigned)f2bf(f.z) | ((unsigned)f2bf(f.w) << 16);
    ((uint2*)out)[i] = make_uint2(lo, hi);
}

// ---------------- bf16 GEMM, C[m,n] = sum_k A[m,k]*B[n,k] (+bias) ----------
// A: M x K (k-contig), B: N x K (k-contig). 128x128 tile, BK=32,
// 256 threads = 4 waves in 2x2, each wave 64x64 = 4x4 MFMA 16x16x32 tiles.
template <bool BF16_OUT, bool BIAS>
__global__ __launch_bounds__(256)
void gemm_bt(const unsigned short* __restrict__ A,
             const unsigned short* __restrict__ Bm,
             void* __restrict__ Cv,
             const float* __restrict__ bias,
             int M, int N, int K)
{
    __shared__ alignas(16) unsigned short As[128 * 32];
    __shared__ alignas(16) unsigned short Bs[128 * 32];
    const int t    = threadIdx.x;
    const int lane = t & 63;
    const int quad = lane >> 4;
    const int r16  = lane & 15;
    const int wave = t >> 6;
    const int wm   = (wave >> 1) * 64;
    const int wn   = (wave & 1) * 64;
    const int m0   = blockIdx.y * 128;
    const int n0   = blockIdx.x * 128;

    // staging chunks: chunk c (0..511) = 8 bf16; row=c>>2, col=(c&3)*8
    const int c0 = t, c1 = t + 256;
    const unsigned short* gA0 = A  + (size_t)(m0 + (c0 >> 2)) * K + (c0 & 3) * 8;
    const unsigned short* gA1 = A  + (size_t)(m0 + (c1 >> 2)) * K + (c1 & 3) * 8;
    const unsigned short* gB0 = Bm + (size_t)(n0 + (c0 >> 2)) * K + (c0 & 3) * 8;
    const unsigned short* gB1 = Bm + (size_t)(n0 + (c1 >> 2)) * K + (c1 & 3) * 8;

    f32x4 acc[4][4] = {};

    for (int k0 = 0; k0 < K; k0 += 32) {
        async16(gA0 + k0, As + c0 * 8);
        async16(gA1 + k0, As + c1 * 8);
        async16(gB0 + k0, Bs + c0 * 8);
        async16(gB1 + k0, Bs + c1 * 8);
        __syncthreads();   // drains vmcnt(0): LDS tiles ready

        short8_t a[4], b[4];
        #pragma unroll
        for (int i = 0; i < 4; ++i)
            a[i] = *(const short8_t*)(As + (wm + i * 16 + r16) * 32 + quad * 8);
        #pragma unroll
        for (int j = 0; j < 4; ++j)
            b[j] = *(const short8_t*)(Bs + (wn + j * 16 + r16) * 32 + quad * 8);
        #pragma unroll
        for (int i = 0; i < 4; ++i)
            #pragma unroll
            for (int j = 0; j < 4; ++j)
                acc[i][j] = __builtin_amdgcn_mfma_f32_16x16x32_bf16(
                    a[i], b[j], acc[i][j], 0, 0, 0);
        __syncthreads();   // all waves done reading before next overwrite
    }

    // C/D layout: col=lane&15 (B index n), row=quad*4+reg (A index m)
    #pragma unroll
    for (int i = 0; i < 4; ++i) {
        #pragma unroll
        for (int j = 0; j < 4; ++j) {
            const int col = n0 + wn + j * 16 + r16;
            float bv = 0.f;
            if constexpr (BIAS) bv = bias[col];
            #pragma unroll
            for (int r = 0; r < 4; ++r) {
                const int row = m0 + wm + i * 16 + quad * 4 + r;
                float v = acc[i][j][r] + bv;
                if constexpr (BF16_OUT)
                    ((unsigned short*)Cv)[(size_t)row * N + col] = f2bf(v);
                else
                    ((float*)Cv)[(size_t)row * N + col] = v;
            }
        }
    }
}

// ---------------- per-token 16-head cross-head attention -------------------
// qkv row (3072 bf16) = [q(16x64) | k(16x64) | v(16x64)], one wave per token.
// S = Q K^T * 0.125 (2 MFMAs), softmax over g, O = P V (4 MFMAs, k padded),
// output written with the swapaxes(1,2).reshape permutation:
//   out[b, h*256 + n/16, (n%16)*64 + hd] = O[h][hd]
__global__ __launch_bounds__(256)
void attn_kernel(const unsigned short* __restrict__ qkv,
                 unsigned short* __restrict__ operm)
{
    __shared__ alignas(16) unsigned short s_qkv[4][QKV_N];
    __shared__ alignas(16) unsigned short s_p[4][256];
    const int t     = threadIdx.x;
    const int lane  = t & 63;
    const int wave  = t >> 6;
    const int quad  = lane >> 4;
    const int r16   = lane & 15;
    const int token = blockIdx.x * 4 + wave;

    { // stage 3072 bf16 = 384 x 16B chunks, 6 per lane, coalesced
        const int4* src = (const int4*)(qkv + (size_t)token * QKV_N);
        int4* dst = (int4*)(&s_qkv[wave][0]);
        #pragma unroll
        for (int i = 0; i < 6; ++i) dst[i * 64 + lane] = src[i * 64 + lane];
    }
    __syncthreads();

    const unsigned short* q  = &s_qkv[wave][0];
    const unsigned short* kk = q + 1024;
    const unsigned short* vv = q + 2048;

    // S = Q K^T : A rows = q heads (m=h), B rows = k heads (n=g)
    f32x4 s = {};
    #pragma unroll
    for (int c = 0; c < 64; c += 32) {
        short8_t aq = *(const short8_t*)(q  + r16 * 64 + c + quad * 8);
        short8_t bk = *(const short8_t*)(kk + r16 * 64 + c + quad * 8);
        s = __builtin_amdgcn_mfma_f32_16x16x32_bf16(aq, bk, s, 0, 0, 0);
    }

    // softmax over g (= col = r16 lanes within each quad group), per reg
    #pragma unroll
    for (int r = 0; r < 4; ++r) {
        float x = s[r] * 0.125f;                 // HD^-0.5
        float m = x;
        #pragma unroll
        for (int o = 1; o < 16; o <<= 1) m = fmaxf(m, __shfl_xor(m, o));
        float e = __expf(x - m);
        float su = e;
        #pragma unroll
        for (int o = 1; o < 16; o <<= 1) su += __shfl_xor(su, o);
        // P[h=quad*4+r][g=r16] -> LDS for C-layout -> A-layout transform
        s_p[wave][(quad * 4 + r) * 16 + r16] = f2bf(e / su);
    }
    __syncthreads();

    // P as A-operand: A[m=r16][k=quad*8+e], k=16..31 zero-padded
    short8_t pa = {};
    if (quad < 2) pa = *(const short8_t*)(&s_p[wave][r16 * 16 + quad * 8]);

    const int b    = token >> 12;
    const int npos = token & 4095;
    const size_t base = (size_t)b * (NSEQ * DM)
                      + (size_t)(npos >> 4) * 1024
                      + (size_t)(npos & 15) * 64;

    #pragma unroll
    for (int j = 0; j < 4; ++j) {
        // B-operand: B[n=d][k=g] = V[g][d], transposed LDS reads; k>=16 -> 0
        short8_t vb = {};
        if (quad < 2) {
            #pragma unroll
            for (int e = 0; e < 8; ++e)
                vb[e] = (short)vv[(quad * 8 + e) * 64 + j * 16 + r16];
        }
        f32x4 z = {};
        f32x4 o = __builtin_amdgcn_mfma_f32_16x16x32_bf16(pa, vb, z, 0, 0, 0);
        #pragma unroll
        for (int r = 0; r < 4; ++r) {
            const int h = quad * 4 + r;          // O row
            operm[base + (size_t)h * (256 * 1024) + j * 16 + r16] = f2bf(o[r]);
        }
    }
}

// ---------------------------------------------------------------------------
extern "C" void kernel_launch(void* const* d_in, const int* in_sizes, int n_in,
                              void* d_out, int out_size, void* d_ws, size_t ws_size,
                              hipStream_t stream)
{
    const float* x      = (const float*)d_in[0];   // 16384 x 1024
    const float* w_qkv  = (const float*)d_in[1];   // 3072 x 1024
    const float* w_proj = (const float*)d_in[2];   // 1024 x 1024
    const float* b_proj = (const float*)d_in[3];   // 1024
    float* out = (float*)d_out;                    // 16384 x 1024 fp32

    // workspace carve (all bf16/ushort); total 88,080,384 elems = 176,160,768 B
    unsigned short* xb     = (unsigned short*)d_ws;            // 16,777,216
    unsigned short* wqkvb  = xb     + (size_t)16777216;        //  3,145,728
    unsigned short* wprojb = wqkvb  + (size_t)3145728;         //  1,048,576
    unsigned short* qkvb   = wprojb + (size_t)1048576;         // 50,331,648
    unsigned short* opermb = qkvb   + (size_t)50331648;        // 16,777,216

    cvt_f32_bf16<<<16777216 / 4 / 256, 256, 0, stream>>>(x, xb, 16777216 / 4);
    cvt_f32_bf16<<<3145728 / 4 / 256, 256, 0, stream>>>(w_qkv, wqkvb, 3145728 / 4);
    cvt_f32_bf16<<<1048576 / 4 / 256, 256, 0, stream>>>(w_proj, wprojb, 1048576 / 4);

    dim3 g1(QKV_N / 128, NTOK / 128);   // (24, 128)
    gemm_bt<true, false><<<g1, 256, 0, stream>>>(xb, wqkvb, qkvb, nullptr,
                                                 NTOK, QKV_N, DM);

    attn_kernel<<<NTOK / 4, 256, 0, stream>>>(qkvb, opermb);

    dim3 g2(DM / 128, NTOK / 128);      // (8, 128)
    gemm_bt<false, true><<<g2, 256, 0, stream>>>(opermb, wprojb, out, b_proj,
                                                 NTOK, DM, DM);
}

// Round 2
// 353.151 us; speedup vs baseline: 1.0074x; 1.0074x over previous
//
#include <hip/hip_runtime.h>
#include <hip/hip_bf16.h>
#include <cstdint>
#include <cstddef>

// Problem constants: B=4, N=4096, D=1024, H=16, HD=64
#define NB      4
#define NSEQ    4096
#define DM      1024
#define NTOK    16384          // B*N
#define QKV_N   3072           // 3*D

typedef __attribute__((ext_vector_type(8))) short short8_t;   // 8 x bf16 bits
typedef __attribute__((ext_vector_type(4))) float f32x4;

static __device__ __forceinline__ unsigned short f2bf(float f) {
    unsigned u = __builtin_bit_cast(unsigned, f);
    u += 0x7fffu + ((u >> 16) & 1u);          // RNE
    return (unsigned short)(u >> 16);
}

static __device__ __forceinline__ void async16(const void* g, void* l) {
    __builtin_amdgcn_global_load_lds(
        (const __attribute__((address_space(1))) void*)g,
        (__attribute__((address_space(3))) void*)l, 16, 0, 0);
}

// ---------------- fused fp32 -> bf16 convert for all three inputs ----------
// x: 4,194,304 float4 | w_qkv: 786,432 | w_proj: 262,144  (total 5,242,880)
__global__ void cvt_all(const float* __restrict__ x,
                        const float* __restrict__ wqkv,
                        const float* __restrict__ wproj,
                        unsigned short* __restrict__ xb,
                        unsigned short* __restrict__ wqkvb,
                        unsigned short* __restrict__ wprojb)
{
    int i = blockIdx.x * blockDim.x + threadIdx.x;
    const float* src; unsigned short* dst; int off;
    if (i < 4194304)      { src = x;     dst = xb;     off = i; }
    else if (i < 4980736) { src = wqkv;  dst = wqkvb;  off = i - 4194304; }
    else                  { src = wproj; dst = wprojb; off = i - 4980736; }
    float4 f = ((const float4*)src)[off];
    unsigned lo = (unsigned)f2bf(f.x) | ((unsigned)f2bf(f.y) << 16);
    unsigned hi = (unsigned)f2bf(f.z) | ((unsigned)f2bf(f.w) << 16);
    ((uint2*)dst)[off] = make_uint2(lo, hi);
}

// ---------------- bf16 GEMM, C[m,n] = sum_k A[m,k]*B[n,k] (+bias) ----------
// A: M x K (k-contig), B: N x K (k-contig). 128x128 tile, BK=32,
// 256 threads = 4 waves in 2x2, each wave 64x64 = 4x4 MFMA 16x16x32 tiles.
template <bool BF16_OUT, bool BIAS>
__global__ __launch_bounds__(256)
void gemm_bt(const unsigned short* __restrict__ A,
             const unsigned short* __restrict__ Bm,
             void* __restrict__ Cv,
             const float* __restrict__ bias,
             int M, int N, int K)
{
    __shared__ alignas(16) unsigned short As[128 * 32];
    __shared__ alignas(16) unsigned short Bs[128 * 32];
    const int t    = threadIdx.x;
    const int lane = t & 63;
    const int quad = lane >> 4;
    const int r16  = lane & 15;
    const int wave = t >> 6;
    const int wm   = (wave >> 1) * 64;
    const int wn   = (wave & 1) * 64;
    const int m0   = blockIdx.y * 128;
    const int n0   = blockIdx.x * 128;

    // staging chunks: chunk c (0..511) = 8 bf16; row=c>>2, col=(c&3)*8
    const int c0 = t, c1 = t + 256;
    const unsigned short* gA0 = A  + (size_t)(m0 + (c0 >> 2)) * K + (c0 & 3) * 8;
    const unsigned short* gA1 = A  + (size_t)(m0 + (c1 >> 2)) * K + (c1 & 3) * 8;
    const unsigned short* gB0 = Bm + (size_t)(n0 + (c0 >> 2)) * K + (c0 & 3) * 8;
    const unsigned short* gB1 = Bm + (size_t)(n0 + (c1 >> 2)) * K + (c1 & 3) * 8;

    f32x4 acc[4][4] = {};

    for (int k0 = 0; k0 < K; k0 += 32) {
        async16(gA0 + k0, As + c0 * 8);
        async16(gA1 + k0, As + c1 * 8);
        async16(gB0 + k0, Bs + c0 * 8);
        async16(gB1 + k0, Bs + c1 * 8);
        __syncthreads();   // drains vmcnt(0): LDS tiles ready

        short8_t a[4], b[4];
        #pragma unroll
        for (int i = 0; i < 4; ++i)
            a[i] = *(const short8_t*)(As + (wm + i * 16 + r16) * 32 + quad * 8);
        #pragma unroll
        for (int j = 0; j < 4; ++j)
            b[j] = *(const short8_t*)(Bs + (wn + j * 16 + r16) * 32 + quad * 8);
        #pragma unroll
        for (int i = 0; i < 4; ++i)
            #pragma unroll
            for (int j = 0; j < 4; ++j)
                acc[i][j] = __builtin_amdgcn_mfma_f32_16x16x32_bf16(
                    a[i], b[j], acc[i][j], 0, 0, 0);
        __syncthreads();   // all waves done reading before next overwrite
    }

    // C/D layout: col=lane&15 (B index n), row=quad*4+reg (A index m)
    #pragma unroll
    for (int i = 0; i < 4; ++i) {
        #pragma unroll
        for (int j = 0; j < 4; ++j) {
            const int col = n0 + wn + j * 16 + r16;
            float bv = 0.f;
            if constexpr (BIAS) bv = bias[col];
            #pragma unroll
            for (int r = 0; r < 4; ++r) {
                const int row = m0 + wm + i * 16 + quad * 4 + r;
                float v = acc[i][j][r] + bv;
                if constexpr (BF16_OUT)
                    ((unsigned short*)Cv)[(size_t)row * N + col] = f2bf(v);
                else
                    ((float*)Cv)[(size_t)row * N + col] = v;
            }
        }
    }
}

// ---------------- per-token 16-head cross-head attention -------------------
// qkv row (3072 bf16) = [q(16x64) | k(16x64) | v(16x64)], one wave per token.
// S = Q K^T * 0.125 (2 MFMAs), softmax over g, O = P V (4 MFMAs, k padded),
// output written with the swapaxes(1,2).reshape permutation:
//   out[b, h*256 + n/16, (n%16)*64 + hd] = O[h][hd]
// O staged through LDS (stride 72 shorts: 2-way write conflicts = free,
// conflict-free b128 reads) -> 2 x dwordx4 coalesced stores per lane.
__global__ __launch_bounds__(256)
void attn_kernel(const unsigned short* __restrict__ qkv,
                 unsigned short* __restrict__ operm)
{
    __shared__ alignas(16) unsigned short s_qkv[4][QKV_N];   // 24 KB
    __shared__ alignas(16) unsigned short s_p[4][256];       //  2 KB
    __shared__ alignas(16) unsigned short s_o[4][16 * 72];   //  9 KB
    const int t     = threadIdx.x;
    const int lane  = t & 63;
    const int wave  = t >> 6;
    const int quad  = lane >> 4;
    const int r16   = lane & 15;
    const int token = blockIdx.x * 4 + wave;

    { // async stage 3072 bf16 = 384 x 16B chunks, 6 per lane (wave-uniform base + lane*16)
        const unsigned short* src = qkv + (size_t)token * QKV_N;
        #pragma unroll
        for (int i = 0; i < 6; ++i)
            async16(src + i * 512 + lane * 8, &s_qkv[wave][i * 512 + lane * 8]);
    }
    __syncthreads();   // drains vmcnt(0)

    const unsigned short* q  = &s_qkv[wave][0];
    const unsigned short* kk = q + 1024;
    const unsigned short* vv = q + 2048;

    // S = Q K^T : A rows = q heads (m=h), B rows = k heads (n=g)
    f32x4 s = {};
    #pragma unroll
    for (int c = 0; c < 64; c += 32) {
        short8_t aq = *(const short8_t*)(q  + r16 * 64 + c + quad * 8);
        short8_t bk = *(const short8_t*)(kk + r16 * 64 + c + quad * 8);
        s = __builtin_amdgcn_mfma_f32_16x16x32_bf16(aq, bk, s, 0, 0, 0);
    }

    // softmax over g (= col = r16 lanes within each quad group), per reg
    #pragma unroll
    for (int r = 0; r < 4; ++r) {
        float x = s[r] * 0.125f;                 // HD^-0.5
        float m = x;
        #pragma unroll
        for (int o = 1; o < 16; o <<= 1) m = fmaxf(m, __shfl_xor(m, o));
        float e = __expf(x - m);
        float su = e;
        #pragma unroll
        for (int o = 1; o < 16; o <<= 1) su += __shfl_xor(su, o);
        // P[h=quad*4+r][g=r16] -> LDS for C-layout -> A-layout transform
        s_p[wave][(quad * 4 + r) * 16 + r16] = f2bf(e * __builtin_amdgcn_rcpf(su));
    }
    __syncthreads();

    // P as A-operand: A[m=r16][k=quad*8+e], k=16..31 zero-padded
    short8_t pa = {};
    if (quad < 2) pa = *(const short8_t*)(&s_p[wave][r16 * 16 + quad * 8]);

    f32x4 o[4];
    #pragma unroll
    for (int j = 0; j < 4; ++j) {
        // B-operand: B[n=d][k=g] = V[g][d], transposed LDS reads (2-way = free)
        short8_t vb = {};
        if (quad < 2) {
            #pragma unroll
            for (int e = 0; e < 8; ++e)
                vb[e] = (short)vv[(quad * 8 + e) * 64 + j * 16 + r16];
        }
        f32x4 z = {};
        o[j] = __builtin_amdgcn_mfma_f32_16x16x32_bf16(pa, vb, z, 0, 0, 0);
    }

    // O (C-layout) -> LDS (stride 72) -> coalesced 16B stores
    #pragma unroll
    for (int j = 0; j < 4; ++j)
        #pragma unroll
        for (int r = 0; r < 4; ++r)
            s_o[wave][(quad * 4 + r) * 72 + j * 16 + r16] = f2bf(o[j][r]);
    __syncthreads();

    const int b    = token >> 12;
    const int npos = token & 4095;
    const size_t base = (size_t)b * (NSEQ * DM)
                      + (size_t)(npos >> 4) * 1024
                      + (size_t)(npos & 15) * 64;
    #pragma unroll
    for (int c = lane; c < 128; c += 64) {
        const int h = c >> 3, part = c & 7;   // 16 rows x 8 chunks of 16B
        int4 val = *(const int4*)(&s_o[wave][h * 72 + part * 8]);
        *(int4*)(operm + base + (size_t)h * (256 * 1024) + part * 8) = val;
    }
}

// ---------------------------------------------------------------------------
extern "C" void kernel_launch(void* const* d_in, const int* in_sizes, int n_in,
                              void* d_out, int out_size, void* d_ws, size_t ws_size,
                              hipStream_t stream)
{
    const float* x      = (const float*)d_in[0];   // 16384 x 1024
    const float* w_qkv  = (const float*)d_in[1];   // 3072 x 1024
    const float* w_proj = (const float*)d_in[2];   // 1024 x 1024
    const float* b_proj = (const float*)d_in[3];   // 1024
    float* out = (float*)d_out;                    // 16384 x 1024 fp32

    // workspace carve (all bf16/ushort); total 88,080,384 elems = 176,160,768 B
    unsigned short* xb     = (unsigned short*)d_ws;            // 16,777,216
    unsigned short* wqkvb  = xb     + (size_t)16777216;        //  3,145,728
    unsigned short* wprojb = wqkvb  + (size_t)3145728;         //  1,048,576
    unsigned short* qkvb   = wprojb + (size_t)1048576;         // 50,331,648
    unsigned short* opermb = qkvb   + (size_t)50331648;        // 16,777,216

    cvt_all<<<20480, 256, 0, stream>>>(x, w_qkv, w_proj, xb, wqkvb, wprojb);

    dim3 g1(QKV_N / 128, NTOK / 128);   // (24, 128)
    gemm_bt<true, false><<<g1, 256, 0, stream>>>(xb, wqkvb, qkvb, nullptr,
                                                 NTOK, QKV_N, DM);

    attn_kernel<<<NTOK / 4, 256, 0, stream>>>(qkvb, opermb);

    dim3 g2(DM / 128, NTOK / 128);      // (8, 128)
    gemm_bt<false, true><<<g2, 256, 0, stream>>>(opermb, wprojb, out, b_proj,
                                                 NTOK, DM, DM);
}

// Round 3
// 330.545 us; speedup vs baseline: 1.0762x; 1.0684x over previous
//
#include <hip/hip_runtime.h>
#include <hip/hip_bf16.h>
#include <cstdint>
#include <cstddef>

// Problem constants: B=4, N=4096, D=1024, H=16, HD=64
#define NB      4
#define NSEQ    4096
#define DM      1024
#define NTOK    16384          // B*N
#define QKV_N   3072           // 3*D

typedef __attribute__((ext_vector_type(8))) short short8_t;   // 8 x bf16 bits
typedef __attribute__((ext_vector_type(4))) float f32x4;

static __device__ __forceinline__ unsigned short f2bf(float f) {
    unsigned u = __builtin_bit_cast(unsigned, f);
    u += 0x7fffu + ((u >> 16) & 1u);          // RNE
    return (unsigned short)(u >> 16);
}

static __device__ __forceinline__ void async16(const void* g, void* l) {
    __builtin_amdgcn_global_load_lds(
        (const __attribute__((address_space(1))) void*)g,
        (__attribute__((address_space(3))) void*)l, 16, 0, 0);
}

// ---------------- fused fp32 -> bf16 convert for all three inputs ----------
__global__ void cvt_all(const float* __restrict__ x,
                        const float* __restrict__ wqkv,
                        const float* __restrict__ wproj,
                        unsigned short* __restrict__ xb,
                        unsigned short* __restrict__ wqkvb,
                        unsigned short* __restrict__ wprojb)
{
    int i = blockIdx.x * blockDim.x + threadIdx.x;
    const float* src; unsigned short* dst; int off;
    if (i < 4194304)      { src = x;     dst = xb;     off = i; }
    else if (i < 4980736) { src = wqkv;  dst = wqkvb;  off = i - 4194304; }
    else                  { src = wproj; dst = wprojb; off = i - 4980736; }
    float4 f = ((const float4*)src)[off];
    unsigned lo = (unsigned)f2bf(f.x) | ((unsigned)f2bf(f.y) << 16);
    unsigned hi = (unsigned)f2bf(f.z) | ((unsigned)f2bf(f.w) << 16);
    ((uint2*)dst)[off] = make_uint2(lo, hi);
}

// ---------------- bf16 GEMM, C[m,n] = sum_k A[m,k]*B[n,k] (+bias) ----------
// A: M x K (k-contig), B: N x K (k-contig). Tile TM x 128, BK=64 as two
// 32-wide stages in SEPARATE 128x32-shaped LDS arrays (keeps m97 bank phase).
// 2 barriers per 64-K (32 MFMA per drain for TM=128, AITER-class density).
// TM=128: 4 waves 2x2, each 64x64 (acc 4x4). TM=64: 4 waves 1x4 in N,
// each 64x32 (acc 4x2) — doubles block count for tail-limited shapes.
template <int TM, bool BF16_OUT, bool BIAS>
__global__ __launch_bounds__(256)
void gemm_bt(const unsigned short* __restrict__ A,
             const unsigned short* __restrict__ Bm,
             void* __restrict__ Cv,
             const float* __restrict__ bias,
             int M, int N, int K)
{
    constexpr int ACH = TM * 4 / 256;          // A 16B-chunks per thread per stage
    constexpr int MJ  = (TM == 128) ? 4 : 2;   // N-tiles per wave
    __shared__ alignas(16) unsigned short As[2][TM * 32];
    __shared__ alignas(16) unsigned short Bs[2][128 * 32];
    const int t    = threadIdx.x;
    const int lane = t & 63;
    const int quad = lane >> 4;
    const int r16  = lane & 15;
    const int wave = t >> 6;
    const int wm   = (TM == 128) ? (wave >> 1) * 64 : 0;
    const int wn   = (TM == 128) ? (wave & 1) * 64 : wave * 32;
    const int m0   = blockIdx.y * TM;
    const int n0   = blockIdx.x * 128;

    // staging chunks: chunk c = 8 bf16; row=c>>2, col=(c&3)*8
    const unsigned short* gA[ACH];
    #pragma unroll
    for (int ca = 0; ca < ACH; ++ca) {
        const int c = t + ca * 256;
        gA[ca] = A + (size_t)(m0 + (c >> 2)) * K + (c & 3) * 8;
    }
    const int c0 = t, c1 = t + 256;
    const unsigned short* gB0 = Bm + (size_t)(n0 + (c0 >> 2)) * K + (c0 & 3) * 8;
    const unsigned short* gB1 = Bm + (size_t)(n0 + (c1 >> 2)) * K + (c1 & 3) * 8;

    f32x4 acc[4][MJ] = {};

    for (int k0 = 0; k0 < K; k0 += 64) {
        #pragma unroll
        for (int s = 0; s < 2; ++s) {
            const int ks = k0 + s * 32;
            #pragma unroll
            for (int ca = 0; ca < ACH; ++ca)
                async16(gA[ca] + ks, &As[s][(t + ca * 256) * 8]);
            async16(gB0 + ks, &Bs[s][c0 * 8]);
            async16(gB1 + ks, &Bs[s][c1 * 8]);
        }
        __syncthreads();   // drains vmcnt(0): both stages resident

        #pragma unroll
        for (int s = 0; s < 2; ++s) {
            short8_t a[4], b[MJ];
            #pragma unroll
            for (int i = 0; i < 4; ++i)
                a[i] = *(const short8_t*)(&As[s][(wm + i * 16 + r16) * 32 + quad * 8]);
            #pragma unroll
            for (int j = 0; j < MJ; ++j)
                b[j] = *(const short8_t*)(&Bs[s][(wn + j * 16 + r16) * 32 + quad * 8]);
            #pragma unroll
            for (int i = 0; i < 4; ++i)
                #pragma unroll
                for (int j = 0; j < MJ; ++j)
                    acc[i][j] = __builtin_amdgcn_mfma_f32_16x16x32_bf16(
                        a[i], b[j], acc[i][j], 0, 0, 0);
        }
        __syncthreads();   // all waves done reading before next overwrite
    }

    // C/D layout: col=lane&15 (B index n), row=quad*4+reg (A index m)
    #pragma unroll
    for (int i = 0; i < 4; ++i) {
        #pragma unroll
        for (int j = 0; j < MJ; ++j) {
            const int col = n0 + wn + j * 16 + r16;
            float bv = 0.f;
            if constexpr (BIAS) bv = bias[col];
            #pragma unroll
            for (int r = 0; r < 4; ++r) {
                const int row = m0 + wm + i * 16 + quad * 4 + r;
                float v = acc[i][j][r] + bv;
                if constexpr (BF16_OUT)
                    ((unsigned short*)Cv)[(size_t)row * N + col] = f2bf(v);
                else
                    ((float*)Cv)[(size_t)row * N + col] = v;
            }
        }
    }
}

// ---------------- per-token 16-head cross-head attention -------------------
// qkv row (3072 bf16) = [q(16x64) | k(16x64) | v(16x64)], one wave per token.
// S = Q K^T * 0.125 (2 MFMAs), softmax over g, O = P V (4 MFMAs, k padded),
// output written with the swapaxes(1,2).reshape permutation:
//   out[b, h*256 + n/16, (n%16)*64 + hd] = O[h][hd]
__global__ __launch_bounds__(256)
void attn_kernel(const unsigned short* __restrict__ qkv,
                 unsigned short* __restrict__ operm)
{
    __shared__ alignas(16) unsigned short s_qkv[4][QKV_N];   // 24 KB
    __shared__ alignas(16) unsigned short s_p[4][256];       //  2 KB
    __shared__ alignas(16) unsigned short s_o[4][16 * 72];   //  9 KB
    const int t     = threadIdx.x;
    const int lane  = t & 63;
    const int wave  = t >> 6;
    const int quad  = lane >> 4;
    const int r16   = lane & 15;
    const int token = blockIdx.x * 4 + wave;

    { // async stage 3072 bf16 = 384 x 16B chunks, 6 per lane
        const unsigned short* src = qkv + (size_t)token * QKV_N;
        #pragma unroll
        for (int i = 0; i < 6; ++i)
            async16(src + i * 512 + lane * 8, &s_qkv[wave][i * 512 + lane * 8]);
    }
    __syncthreads();

    const unsigned short* q  = &s_qkv[wave][0];
    const unsigned short* kk = q + 1024;
    const unsigned short* vv = q + 2048;

    // S = Q K^T : A rows = q heads (m=h), B rows = k heads (n=g)
    f32x4 s = {};
    #pragma unroll
    for (int c = 0; c < 64; c += 32) {
        short8_t aq = *(const short8_t*)(q  + r16 * 64 + c + quad * 8);
        short8_t bk = *(const short8_t*)(kk + r16 * 64 + c + quad * 8);
        s = __builtin_amdgcn_mfma_f32_16x16x32_bf16(aq, bk, s, 0, 0, 0);
    }

    // softmax over g (= col = r16 lanes within each quad group), per reg
    #pragma unroll
    for (int r = 0; r < 4; ++r) {
        float x = s[r] * 0.125f;                 // HD^-0.5
        float m = x;
        #pragma unroll
        for (int o = 1; o < 16; o <<= 1) m = fmaxf(m, __shfl_xor(m, o));
        float e = __expf(x - m);
        float su = e;
        #pragma unroll
        for (int o = 1; o < 16; o <<= 1) su += __shfl_xor(su, o);
        s_p[wave][(quad * 4 + r) * 16 + r16] = f2bf(e * __builtin_amdgcn_rcpf(su));
    }
    __syncthreads();

    // P as A-operand: A[m=r16][k=quad*8+e], k=16..31 zero-padded
    short8_t pa = {};
    if (quad < 2) pa = *(const short8_t*)(&s_p[wave][r16 * 16 + quad * 8]);

    f32x4 o[4];
    #pragma unroll
    for (int j = 0; j < 4; ++j) {
        // B-operand: B[n=d][k=g] = V[g][d], transposed LDS reads (2-way = free)
        short8_t vb = {};
        if (quad < 2) {
            #pragma unroll
            for (int e = 0; e < 8; ++e)
                vb[e] = (short)vv[(quad * 8 + e) * 64 + j * 16 + r16];
        }
        f32x4 z = {};
        o[j] = __builtin_amdgcn_mfma_f32_16x16x32_bf16(pa, vb, z, 0, 0, 0);
    }

    // O (C-layout) -> LDS (stride 72) -> coalesced 16B stores
    #pragma unroll
    for (int j = 0; j < 4; ++j)
        #pragma unroll
        for (int r = 0; r < 4; ++r)
            s_o[wave][(quad * 4 + r) * 72 + j * 16 + r16] = f2bf(o[j][r]);
    __syncthreads();

    const int b    = token >> 12;
    const int npos = token & 4095;
    const size_t base = (size_t)b * (NSEQ * DM)
                      + (size_t)(npos >> 4) * 1024
                      + (size_t)(npos & 15) * 64;
    #pragma unroll
    for (int c = lane; c < 128; c += 64) {
        const int h = c >> 3, part = c & 7;   // 16 rows x 8 chunks of 16B
        int4 val = *(const int4*)(&s_o[wave][h * 72 + part * 8]);
        *(int4*)(operm + base + (size_t)h * (256 * 1024) + part * 8) = val;
    }
}

// ---------------------------------------------------------------------------
extern "C" void kernel_launch(void* const* d_in, const int* in_sizes, int n_in,
                              void* d_out, int out_size, void* d_ws, size_t ws_size,
                              hipStream_t stream)
{
    const float* x      = (const float*)d_in[0];   // 16384 x 1024
    const float* w_qkv  = (const float*)d_in[1];   // 3072 x 1024
    const float* w_proj = (const float*)d_in[2];   // 1024 x 1024
    const float* b_proj = (const float*)d_in[3];   // 1024
    float* out = (float*)d_out;                    // 16384 x 1024 fp32

    unsigned short* xb     = (unsigned short*)d_ws;            // 16,777,216
    unsigned short* wqkvb  = xb     + (size_t)16777216;        //  3,145,728
    unsigned short* wprojb = wqkvb  + (size_t)3145728;         //  1,048,576
    unsigned short* qkvb   = wprojb + (size_t)1048576;         // 50,331,648
    unsigned short* opermb = qkvb   + (size_t)50331648;        // 16,777,216

    cvt_all<<<20480, 256, 0, stream>>>(x, w_qkv, w_proj, xb, wqkvb, wprojb);

    dim3 g1(QKV_N / 128, NTOK / 128);   // (24, 128)
    gemm_bt<128, true, false><<<g1, 256, 0, stream>>>(xb, wqkvb, qkvb, nullptr,
                                                      NTOK, QKV_N, DM);

    attn_kernel<<<NTOK / 4, 256, 0, stream>>>(qkvb, opermb);

    dim3 g2(DM / 128, NTOK / 64);       // (8, 256) = 2048 blocks
    gemm_bt<64, false, true><<<g2, 256, 0, stream>>>(opermb, wprojb, out, b_proj,
                                                     NTOK, DM, DM);
}

// Round 4
// 326.854 us; speedup vs baseline: 1.0884x; 1.0113x over previous
//
#include <hip/hip_runtime.h>
#include <hip/hip_bf16.h>
#include <cstdint>
#include <cstddef>

// Problem constants: B=4, N=4096, D=1024, H=16, HD=64
#define NB      4
#define NSEQ    4096
#define DM      1024
#define NTOK    16384          // B*N
#define QKV_N   3072           // 3*D

typedef __attribute__((ext_vector_type(8))) short short8_t;   // 8 x bf16 bits
typedef __attribute__((ext_vector_type(4))) float f32x4;

static __device__ __forceinline__ unsigned short f2bf(float f) {
    unsigned u = __builtin_bit_cast(unsigned, f);
    u += 0x7fffu + ((u >> 16) & 1u);          // RNE
    return (unsigned short)(u >> 16);
}

static __device__ __forceinline__ void async16(const void* g, void* l) {
    __builtin_amdgcn_global_load_lds(
        (const __attribute__((address_space(1))) void*)g,
        (__attribute__((address_space(3))) void*)l, 16, 0, 0);
}

// ---------------- fused fp32 -> bf16 convert for all three inputs ----------
__global__ void cvt_all(const float* __restrict__ x,
                        const float* __restrict__ wqkv,
                        const float* __restrict__ wproj,
                        unsigned short* __restrict__ xb,
                        unsigned short* __restrict__ wqkvb,
                        unsigned short* __restrict__ wprojb)
{
    int i = blockIdx.x * blockDim.x + threadIdx.x;
    const float* src; unsigned short* dst; int off;
    if (i < 4194304)      { src = x;     dst = xb;     off = i; }
    else if (i < 4980736) { src = wqkv;  dst = wqkvb;  off = i - 4194304; }
    else                  { src = wproj; dst = wprojb; off = i - 4980736; }
    float4 f = ((const float4*)src)[off];
    unsigned lo = (unsigned)f2bf(f.x) | ((unsigned)f2bf(f.y) << 16);
    unsigned hi = (unsigned)f2bf(f.z) | ((unsigned)f2bf(f.w) << 16);
    ((uint2*)dst)[off] = make_uint2(lo, hi);
}

// ---------------- bf16 GEMM, C[m,n] = sum_k A[m,k]*B[n,k] (+bias) ----------
// A: M x K (k-contig), B: N x K (k-contig). 128x128 tile, BK=64 as two
// 32-wide stages in separate 128x32 LDS arrays. XOR-swizzled LDS columns:
// global k-block q of tile-row r lands at LDS col q ^ f(r), f(r)=(r&3)^((r>>2)&3).
// Staging folds the swizzle into the global source pointer (async16 dst is the
// mandatory lane-contiguous pattern); fragment reads use col quad^f, where f
// collapses to the per-thread constant (r16&3)^((r16>>2)&3). Bank aliasing
// drops from 8-way to 2-way (= free per m136).
template <bool BF16_OUT, bool BIAS>
__global__ __launch_bounds__(256)
void gemm_bt(const unsigned short* __restrict__ A,
             const unsigned short* __restrict__ Bm,
             void* __restrict__ Cv,
             const float* __restrict__ bias,
             int M, int N, int K)
{
    __shared__ alignas(16) unsigned short As[2][128 * 32];
    __shared__ alignas(16) unsigned short Bs[2][128 * 32];
    const int t    = threadIdx.x;
    const int lane = t & 63;
    const int quad = lane >> 4;
    const int r16  = lane & 15;
    const int wave = t >> 6;
    const int wm   = (wave >> 1) * 64;
    const int wn   = (wave & 1) * 64;
    const int m0   = blockIdx.y * 128;
    const int n0   = blockIdx.x * 128;

    // staging chunks: chunk c (0..511) = 8 bf16; LDS row=c>>2, LDS col=c&3.
    // source k-block = (c&3) ^ f(row)  (XOR is involutive)
    const int c0 = t, c1 = t + 256;
    const int ra0 = c0 >> 2, ra1 = c1 >> 2;
    const int f0 = (ra0 & 3) ^ ((ra0 >> 2) & 3);
    const int f1 = (ra1 & 3) ^ ((ra1 >> 2) & 3);
    const unsigned short* gA0 = A  + (size_t)(m0 + ra0) * K + (((c0 & 3) ^ f0)) * 8;
    const unsigned short* gA1 = A  + (size_t)(m0 + ra1) * K + (((c1 & 3) ^ f1)) * 8;
    const unsigned short* gB0 = Bm + (size_t)(n0 + ra0) * K + (((c0 & 3) ^ f0)) * 8;
    const unsigned short* gB1 = Bm + (size_t)(n0 + ra1) * K + (((c1 & 3) ^ f1)) * 8;

    // read-side swizzled column offset (shorts): f is i/j-independent because
    // wm, wn, i*16 are multiples of 16 -> f = (r16&3)^((r16>>2)&3)
    const int qa = ((quad ^ ((r16 & 3) ^ ((r16 >> 2) & 3))) * 8);

    f32x4 acc[4][4] = {};

    for (int k0 = 0; k0 < K; k0 += 64) {
        #pragma unroll
        for (int s = 0; s < 2; ++s) {
            const int ks = k0 + s * 32;
            async16(gA0 + ks, &As[s][c0 * 8]);
            async16(gA1 + ks, &As[s][c1 * 8]);
            async16(gB0 + ks, &Bs[s][c0 * 8]);
            async16(gB1 + ks, &Bs[s][c1 * 8]);
        }
        __syncthreads();   // drains vmcnt(0): both stages resident

        #pragma unroll
        for (int s = 0; s < 2; ++s) {
            short8_t a[4], b[4];
            #pragma unroll
            for (int i = 0; i < 4; ++i)
                a[i] = *(const short8_t*)(&As[s][(wm + i * 16 + r16) * 32 + qa]);
            #pragma unroll
            for (int j = 0; j < 4; ++j)
                b[j] = *(const short8_t*)(&Bs[s][(wn + j * 16 + r16) * 32 + qa]);
            #pragma unroll
            for (int i = 0; i < 4; ++i)
                #pragma unroll
                for (int j = 0; j < 4; ++j)
                    acc[i][j] = __builtin_amdgcn_mfma_f32_16x16x32_bf16(
                        a[i], b[j], acc[i][j], 0, 0, 0);
        }
        __syncthreads();   // all waves done reading before next overwrite
    }

    // C/D layout: col=lane&15 (B index n), row=quad*4+reg (A index m)
    #pragma unroll
    for (int i = 0; i < 4; ++i) {
        #pragma unroll
        for (int j = 0; j < 4; ++j) {
            const int col = n0 + wn + j * 16 + r16;
            float bv = 0.f;
            if constexpr (BIAS) bv = bias[col];
            #pragma unroll
            for (int r = 0; r < 4; ++r) {
                const int row = m0 + wm + i * 16 + quad * 4 + r;
                float v = acc[i][j][r] + bv;
                if constexpr (BF16_OUT)
                    ((unsigned short*)Cv)[(size_t)row * N + col] = f2bf(v);
                else
                    ((float*)Cv)[(size_t)row * N + col] = v;
            }
        }
    }
}

// ---------------- per-token 16-head cross-head attention -------------------
// qkv row (3072 bf16) = [q(16x64) | k(16x64) | v(16x64)], one wave per token.
// S = Q K^T * 0.125 (2 MFMAs), softmax over g, O = P V (4 MFMAs, k padded),
// output written with the swapaxes(1,2).reshape permutation:
//   out[b, h*256 + n/16, (n%16)*64 + hd] = O[h][hd]
__global__ __launch_bounds__(256)
void attn_kernel(const unsigned short* __restrict__ qkv,
                 unsigned short* __restrict__ operm)
{
    __shared__ alignas(16) unsigned short s_qkv[4][QKV_N];   // 24 KB
    __shared__ alignas(16) unsigned short s_p[4][256];       //  2 KB
    __shared__ alignas(16) unsigned short s_o[4][16 * 72];   //  9 KB
    const int t     = threadIdx.x;
    const int lane  = t & 63;
    const int wave  = t >> 6;
    const int quad  = lane >> 4;
    const int r16   = lane & 15;
    const int token = blockIdx.x * 4 + wave;

    { // async stage 3072 bf16 = 384 x 16B chunks, 6 per lane
        const unsigned short* src = qkv + (size_t)token * QKV_N;
        #pragma unroll
        for (int i = 0; i < 6; ++i)
            async16(src + i * 512 + lane * 8, &s_qkv[wave][i * 512 + lane * 8]);
    }
    __syncthreads();

    const unsigned short* q  = &s_qkv[wave][0];
    const unsigned short* kk = q + 1024;
    const unsigned short* vv = q + 2048;

    // S = Q K^T : A rows = q heads (m=h), B rows = k heads (n=g)
    f32x4 s = {};
    #pragma unroll
    for (int c = 0; c < 64; c += 32) {
        short8_t aq = *(const short8_t*)(q  + r16 * 64 + c + quad * 8);
        short8_t bk = *(const short8_t*)(kk + r16 * 64 + c + quad * 8);
        s = __builtin_amdgcn_mfma_f32_16x16x32_bf16(aq, bk, s, 0, 0, 0);
    }

    // softmax over g (= col = r16 lanes within each quad group), per reg
    #pragma unroll
    for (int r = 0; r < 4; ++r) {
        float x = s[r] * 0.125f;                 // HD^-0.5
        float m = x;
        #pragma unroll
        for (int o = 1; o < 16; o <<= 1) m = fmaxf(m, __shfl_xor(m, o));
        float e = __expf(x - m);
        float su = e;
        #pragma unroll
        for (int o = 1; o < 16; o <<= 1) su += __shfl_xor(su, o);
        s_p[wave][(quad * 4 + r) * 16 + r16] = f2bf(e * __builtin_amdgcn_rcpf(su));
    }
    __syncthreads();

    // P as A-operand: A[m=r16][k=quad*8+e], k=16..31 zero-padded
    short8_t pa = {};
    if (quad < 2) pa = *(const short8_t*)(&s_p[wave][r16 * 16 + quad * 8]);

    f32x4 o[4];
    #pragma unroll
    for (int j = 0; j < 4; ++j) {
        // B-operand: B[n=d][k=g] = V[g][d], transposed LDS reads (2-way = free)
        short8_t vb = {};
        if (quad < 2) {
            #pragma unroll
            for (int e = 0; e < 8; ++e)
                vb[e] = (short)vv[(quad * 8 + e) * 64 + j * 16 + r16];
        }
        f32x4 z = {};
        o[j] = __builtin_amdgcn_mfma_f32_16x16x32_bf16(pa, vb, z, 0, 0, 0);
    }

    // O (C-layout) -> LDS (stride 72) -> coalesced 16B stores
    #pragma unroll
    for (int j = 0; j < 4; ++j)
        #pragma unroll
        for (int r = 0; r < 4; ++r)
            s_o[wave][(quad * 4 + r) * 72 + j * 16 + r16] = f2bf(o[j][r]);
    __syncthreads();

    const int b    = token >> 12;
    const int npos = token & 4095;
    const size_t base = (size_t)b * (NSEQ * DM)
                      + (size_t)(npos >> 4) * 1024
                      + (size_t)(npos & 15) * 64;
    #pragma unroll
    for (int c = lane; c < 128; c += 64) {
        const int h = c >> 3, part = c & 7;   // 16 rows x 8 chunks of 16B
        int4 val = *(const int4*)(&s_o[wave][h * 72 + part * 8]);
        *(int4*)(operm + base + (size_t)h * (256 * 1024) + part * 8) = val;
    }
}

// ---------------------------------------------------------------------------
extern "C" void kernel_launch(void* const* d_in, const int* in_sizes, int n_in,
                              void* d_out, int out_size, void* d_ws, size_t ws_size,
                              hipStream_t stream)
{
    const float* x      = (const float*)d_in[0];   // 16384 x 1024
    const float* w_qkv  = (const float*)d_in[1];   // 3072 x 1024
    const float* w_proj = (const float*)d_in[2];   // 1024 x 1024
    const float* b_proj = (const float*)d_in[3];   // 1024
    float* out = (float*)d_out;                    // 16384 x 1024 fp32

    unsigned short* xb     = (unsigned short*)d_ws;            // 16,777,216
    unsigned short* wqkvb  = xb     + (size_t)16777216;        //  3,145,728
    unsigned short* wprojb = wqkvb  + (size_t)3145728;         //  1,048,576
    unsigned short* qkvb   = wprojb + (size_t)1048576;         // 50,331,648
    unsigned short* opermb = qkvb   + (size_t)50331648;        // 16,777,216

    cvt_all<<<20480, 256, 0, stream>>>(x, w_qkv, w_proj, xb, wqkvb, wprojb);

    dim3 g1(QKV_N / 128, NTOK / 128);   // (24, 128)
    gemm_bt<true, false><<<g1, 256, 0, stream>>>(xb, wqkvb, qkvb, nullptr,
                                                 NTOK, QKV_N, DM);

    attn_kernel<<<NTOK / 4, 256, 0, stream>>>(qkvb, opermb);

    dim3 g2(DM / 128, NTOK / 128);      // (8, 128)
    gemm_bt<false, true><<<g2, 256, 0, stream>>>(opermb, wprojb, out, b_proj,
                                                 NTOK, DM, DM);
}